// Round 2
// baseline (1723.925 us; speedup 1.0000x reference)
//
#include <hip/hip_runtime.h>
#include <hip/hip_bf16.h>
#include <math.h>

#define HEADS 4
#define D_HEAD 32
#define HD 128          // HEADS*D_HEAD
#define D_IN 128
#define OUT_DIM 512
#define NEG_SLOPE 0.2f
#define EPS 1e-9f

// ---------- helpers: monotone float<->uint encoding for atomic max ----------
__device__ __forceinline__ unsigned f2mono(float f) {
    unsigned u = __float_as_uint(f);
    return (u & 0x80000000u) ? ~u : (u | 0x80000000u);
}
__device__ __forceinline__ float mono2f(unsigned u) {
    return (u & 0x80000000u) ? __uint_as_float(u & 0x7fffffffu)
                             : __uint_as_float(~u);
}
#define MONO_NEG_INF 0x007FFFFFu   // f2mono(-inf)

__device__ __forceinline__ float lrelu(float x) { return x > 0.f ? x : NEG_SLOPE * x; }

// ---------- node GEMM: Wh = X @ W  (N x 128 @ 128 x 128), fused el/er ----------
// block = 256 threads, NPB = 32 nodes per block.
#define NPB 32
__global__ __launch_bounds__(256) void gemm_node(
    const float* __restrict__ X, const float* __restrict__ W,
    const float* __restrict__ al, const float* __restrict__ ar,
    float* __restrict__ Wh, float* __restrict__ el, float* __restrict__ er, int N)
{
    __shared__ float Ws[64][128];    // 32 KB (half of W at a time)
    __shared__ float hs[NPB][128];   // 16 KB

    const int tid = threadIdx.x;
    const int j   = tid & 127;       // output column
    const int sub = tid >> 7;        // 0/1: which node of each pair
    const int node0 = blockIdx.x * NPB;

    // load all NPB node rows
    for (int i = tid; i < NPB * 128; i += 256) {
        int ln = i >> 7, c = i & 127;
        int n = node0 + ln;
        hs[ln][c] = (n < N) ? X[(size_t)n * 128 + c] : 0.f;
    }

    float acc[NPB / 2];
#pragma unroll
    for (int it = 0; it < NPB / 2; ++it) acc[it] = 0.f;

    for (int kb = 0; kb < 128; kb += 64) {
        __syncthreads();
        for (int i = tid; i < 64 * 128; i += 256)
            Ws[i >> 7][i & 127] = W[(size_t)(kb + (i >> 7)) * 128 + (i & 127)];
        __syncthreads();
#pragma unroll
        for (int it = 0; it < NPB / 2; ++it) {
            const int ln = 2 * it + sub;
            float a = acc[it];
#pragma unroll
            for (int k = 0; k < 64; ++k)
                a += hs[ln][kb + k] * Ws[k][j];
            acc[it] = a;
        }
    }

    const int hh = j >> 5, d = j & 31;
    const float alv = al[hh * 32 + d];
    const float arv = ar[hh * 32 + d];
#pragma unroll
    for (int it = 0; it < NPB / 2; ++it) {
        const int n = node0 + 2 * it + sub;
        if (n < N) {
            const float a = acc[it];
            Wh[(size_t)n * 128 + j] = a;
            float pl = a * alv, pr = a * arv;
#pragma unroll
            for (int off = 16; off; off >>= 1) {
                pl += __shfl_down(pl, off, 32);
                pr += __shfl_down(pr, off, 32);
            }
            if (d == 0) {
                el[(size_t)n * 4 + hh] = pl;
                er[(size_t)n * 4 + hh] = pr;
            }
        }
    }
}

// ---------- per-layer init: zero agg/denom, set m = mono(-inf) ----------
__global__ void init_layer(float* __restrict__ agg, float* __restrict__ denom,
                           unsigned* __restrict__ m, int N)
{
    int t = blockIdx.x * 256 + threadIdx.x;
    if (t < N * HD) agg[t] = 0.f;
    if (t < N * HEADS) { denom[t] = 0.f; m[t] = MONO_NEG_INF; }
}

// ---------- edge pass A: e = leakyrelu(el[src]+er[dst]); atomic max into m ----------
__global__ void edge_logits(const int* __restrict__ src, const int* __restrict__ dst,
                            const float* __restrict__ el, const float* __restrict__ er,
                            float* __restrict__ e_out, unsigned* __restrict__ m, int E)
{
    int eid = blockIdx.x * 256 + threadIdx.x;
    if (eid >= E) return;
    int s = src[eid], d = dst[eid];
    float4 a = *(const float4*)(el + 4 * (size_t)s);
    float4 b = *(const float4*)(er + 4 * (size_t)d);
    float4 ev;
    ev.x = lrelu(a.x + b.x);
    ev.y = lrelu(a.y + b.y);
    ev.z = lrelu(a.z + b.z);
    ev.w = lrelu(a.w + b.w);
    *(float4*)(e_out + 4 * (size_t)eid) = ev;
    unsigned* mb = m + 4 * (size_t)d;
    atomicMax(mb + 0, f2mono(ev.x));
    atomicMax(mb + 1, f2mono(ev.y));
    atomicMax(mb + 2, f2mono(ev.z));
    atomicMax(mb + 3, f2mono(ev.w));
}

// ---------- edge pass B: ex = exp(e - m[dst]); atomicAdd denom ----------
__global__ void edge_exp(const int* __restrict__ dst, const unsigned* __restrict__ m,
                         float* __restrict__ e_inout, float* __restrict__ denom, int E)
{
    int eid = blockIdx.x * 256 + threadIdx.x;
    if (eid >= E) return;
    int d = dst[eid];
    float4 ev = *(const float4*)(e_inout + 4 * (size_t)eid);
    uint4 mu = *(const uint4*)(m + 4 * (size_t)d);
    float4 e2;
    e2.x = expf(ev.x - mono2f(mu.x));
    e2.y = expf(ev.y - mono2f(mu.y));
    e2.z = expf(ev.z - mono2f(mu.z));
    e2.w = expf(ev.w - mono2f(mu.w));
    *(float4*)(e_inout + 4 * (size_t)eid) = e2;
    float* db = denom + 4 * (size_t)d;
    atomicAdd(db + 0, e2.x);
    atomicAdd(db + 1, e2.y);
    atomicAdd(db + 2, e2.z);
    atomicAdd(db + 3, e2.w);
}

// ---------- edge pass C: agg[dst] += alpha * Wh[src] ----------
__global__ void edge_aggregate(const int* __restrict__ src, const int* __restrict__ dst,
                               const float* __restrict__ ex, const float* __restrict__ denom,
                               const float* __restrict__ Wh, float* __restrict__ agg, int E)
{
    long t = (long)blockIdx.x * 256 + threadIdx.x;
    if (t >= (long)E * 128) return;
    int eid = (int)(t >> 7);
    int j   = (int)(t & 127);
    int hh  = j >> 5;
    int s = src[eid], d = dst[eid];
    float alpha = ex[4 * (size_t)eid + hh] / (denom[4 * (size_t)d + hh] + EPS);
    atomicAdd(agg + 128 * (size_t)d + j, alpha * Wh[128 * (size_t)s + j]);
}

// ---------- elementwise: z = elu(agg + b) ----------
__global__ void elu_bias(const float* __restrict__ agg, const float* __restrict__ b,
                         float* __restrict__ z, int total)
{
    int t = blockIdx.x * 256 + threadIdx.x;
    if (t >= total) return;
    float x = agg[t] + b[t & 127];
    z[t] = x > 0.f ? x : expm1f(x);
}

// ---------- mean over heads: z2[n,d] = mean_h(agg[n,h,d] + b[h,d]) ----------
__global__ void mean_heads(const float* __restrict__ agg, const float* __restrict__ b,
                           float* __restrict__ z2, int N)
{
    int t = blockIdx.x * 256 + threadIdx.x;
    if (t >= N * 32) return;
    int n = t >> 5, d = t & 31;
    float s = 0.f;
#pragma unroll
    for (int h = 0; h < HEADS; ++h)
        s += agg[(size_t)n * 128 + h * 32 + d] + b[h * 32 + d];
    z2[t] = 0.25f * s;
}

// ---------- final projection: out = z2 @ Wp + bp  (N x 32 @ 32 x 512) ----------
#define NPBP 64
__global__ __launch_bounds__(256) void proj(
    const float* __restrict__ z2, const float* __restrict__ Wp,
    const float* __restrict__ bp, float* __restrict__ out, int N)
{
    __shared__ float Ws[32][256];   // 32 KB (half of Wp)
    __shared__ float zs[NPBP][32];  // 8 KB
    const int tid = threadIdx.x;
    const int node0 = blockIdx.x * NPBP;

    for (int i = tid; i < NPBP * 32; i += 256) {
        int ln = i >> 5, c = i & 31;
        int n = node0 + ln;
        zs[ln][c] = (n < N) ? z2[(size_t)n * 32 + c] : 0.f;
    }
    for (int half = 0; half < 2; ++half) {
        __syncthreads();
        for (int i = tid; i < 32 * 256; i += 256) {
            int d = i >> 8, o = i & 255;
            Ws[d][o] = Wp[(size_t)d * 512 + half * 256 + o];
        }
        __syncthreads();
        const int o = tid;
        const float bv = bp[half * 256 + o];
        for (int ln = 0; ln < NPBP; ++ln) {
            int n = node0 + ln;
            if (n >= N) break;
            float acc = bv;
#pragma unroll
            for (int d = 0; d < 32; ++d)
                acc += zs[ln][d] * Ws[d][o];
            out[(size_t)n * 512 + half * 256 + o] = acc;
        }
    }
}

extern "C" void kernel_launch(void* const* d_in, const int* in_sizes, int n_in,
                              void* d_out, int out_size, void* d_ws, size_t ws_size,
                              hipStream_t stream)
{
    const float* h   = (const float*)d_in[0];
    const int*   src = (const int*)d_in[1];
    const int*   dst = (const int*)d_in[2];
    const float* W1  = (const float*)d_in[3];
    const float* al1 = (const float*)d_in[4];
    const float* ar1 = (const float*)d_in[5];
    const float* b1  = (const float*)d_in[6];
    const float* W2  = (const float*)d_in[7];
    const float* al2 = (const float*)d_in[8];
    const float* ar2 = (const float*)d_in[9];
    const float* b2  = (const float*)d_in[10];
    const float* Wp  = (const float*)d_in[11];
    const float* bp  = (const float*)d_in[12];
    float* out = (float*)d_out;

    const int N = in_sizes[0] / D_IN;   // 50000
    const int E = in_sizes[1];          // 800000

    float* ws = (float*)d_ws;
    size_t off = 0;
    float* Wh    = ws + off; off += (size_t)N * 128;
    float* agg   = ws + off; off += (size_t)N * 128;
    float* z     = ws + off; off += (size_t)N * 128;
    float* ebuf  = ws + off; off += (size_t)E * 4;
    float* el    = ws + off; off += (size_t)N * 4;
    float* er    = ws + off; off += (size_t)N * 4;
    float* denom = ws + off; off += (size_t)N * 4;
    unsigned* m  = (unsigned*)(ws + off); off += (size_t)N * 4;
    float* z2 = Wh;  // alias: Wh dead after layer-2 aggregation

    const int gemm_grid = (N + NPB - 1) / NPB;
    const int nodeE_grid = (N * 128 + 255) / 256;
    const int edge_grid = (E + 255) / 256;
    const long aggT = (long)E * 128;
    const int agg_grid = (int)((aggT + 255) / 256);

    // ----- layer 1 -----
    gemm_node<<<gemm_grid, 256, 0, stream>>>(h, W1, al1, ar1, Wh, el, er, N);
    init_layer<<<nodeE_grid, 256, 0, stream>>>(agg, denom, m, N);
    edge_logits<<<edge_grid, 256, 0, stream>>>(src, dst, el, er, ebuf, m, E);
    edge_exp<<<edge_grid, 256, 0, stream>>>(dst, m, ebuf, denom, E);
    edge_aggregate<<<agg_grid, 256, 0, stream>>>(src, dst, ebuf, denom, Wh, agg, E);
    elu_bias<<<nodeE_grid, 256, 0, stream>>>(agg, b1, z, N * 128);

    // ----- layer 2 -----
    gemm_node<<<gemm_grid, 256, 0, stream>>>(z, W2, al2, ar2, Wh, el, er, N);
    init_layer<<<nodeE_grid, 256, 0, stream>>>(agg, denom, m, N);
    edge_logits<<<edge_grid, 256, 0, stream>>>(src, dst, el, er, ebuf, m, E);
    edge_exp<<<edge_grid, 256, 0, stream>>>(dst, m, ebuf, denom, E);
    edge_aggregate<<<agg_grid, 256, 0, stream>>>(src, dst, ebuf, denom, Wh, agg, E);
    mean_heads<<<(N * 32 + 255) / 256, 256, 0, stream>>>(agg, b2, z2, N);

    // ----- projection -----
    proj<<<(N + NPBP - 1) / NPBP, 256, 0, stream>>>(z2, Wp, bp, out, N);
}

// Round 3
// 769.637 us; speedup vs baseline: 2.2399x; 2.2399x over previous
//
#include <hip/hip_runtime.h>
#include <hip/hip_bf16.h>
#include <math.h>

#define HEADS 4
#define D_HEAD 32
#define HD 128          // HEADS*D_HEAD
#define D_IN 128
#define OUT_DIM 512
#define NEG_SLOPE 0.2f
#define EPS 1e-9f

__device__ __forceinline__ float lrelu(float x) { return x > 0.f ? x : NEG_SLOPE * x; }

// ---------- node GEMM: Wh = X @ W  (N x 128 @ 128 x 128), fused el/er ----------
#define NPB 32
__global__ __launch_bounds__(256) void gemm_node(
    const float* __restrict__ X, const float* __restrict__ W,
    const float* __restrict__ al, const float* __restrict__ ar,
    float* __restrict__ Wh, float* __restrict__ el, float* __restrict__ er, int N)
{
    __shared__ float Ws[64][128];    // 32 KB (half of W at a time)
    __shared__ float hs[NPB][128];   // 16 KB

    const int tid = threadIdx.x;
    const int j   = tid & 127;       // output column
    const int sub = tid >> 7;        // 0/1: which node of each pair
    const int node0 = blockIdx.x * NPB;

    for (int i = tid; i < NPB * 128; i += 256) {
        int ln = i >> 7, c = i & 127;
        int n = node0 + ln;
        hs[ln][c] = (n < N) ? X[(size_t)n * 128 + c] : 0.f;
    }

    float acc[NPB / 2];
#pragma unroll
    for (int it = 0; it < NPB / 2; ++it) acc[it] = 0.f;

    for (int kb = 0; kb < 128; kb += 64) {
        __syncthreads();
        for (int i = tid; i < 64 * 128; i += 256)
            Ws[i >> 7][i & 127] = W[(size_t)(kb + (i >> 7)) * 128 + (i & 127)];
        __syncthreads();
#pragma unroll
        for (int it = 0; it < NPB / 2; ++it) {
            const int ln = 2 * it + sub;
            float a = acc[it];
#pragma unroll
            for (int k = 0; k < 64; ++k)
                a += hs[ln][kb + k] * Ws[k][j];
            acc[it] = a;
        }
    }

    const int hh = j >> 5, d = j & 31;
    const float alv = al[hh * 32 + d];
    const float arv = ar[hh * 32 + d];
#pragma unroll
    for (int it = 0; it < NPB / 2; ++it) {
        const int n = node0 + 2 * it + sub;
        if (n < N) {
            const float a = acc[it];
            Wh[(size_t)n * 128 + j] = a;
            float pl = a * alv, pr = a * arv;
#pragma unroll
            for (int off = 16; off; off >>= 1) {
                pl += __shfl_down(pl, off, 32);
                pr += __shfl_down(pr, off, 32);
            }
            if (d == 0) {
                el[(size_t)n * 4 + hh] = pl;
                er[(size_t)n * 4 + hh] = pr;
            }
        }
    }
}

// ---------- CSR build ----------
__global__ void zero_ints(int* __restrict__ p, int n)
{
    int t = blockIdx.x * 256 + threadIdx.x;
    if (t < n) p[t] = 0;
}

__global__ void hist_dst(const int* __restrict__ dst, int* __restrict__ deg, int E)
{
    int e = blockIdx.x * 256 + threadIdx.x;
    if (e < E) atomicAdd(&deg[dst[e]], 1);
}

// single-block exclusive scan of deg[0..N) -> rowptr[0..N]
__global__ __launch_bounds__(1024) void scan_deg(const int* __restrict__ deg,
                                                 int* __restrict__ rowptr, int N)
{
    __shared__ int sums[1024];
    const int t = threadIdx.x;
    const int chunk = (N + 1023) / 1024;
    const int lo = t * chunk;
    const int hi = min(lo + chunk, N);
    int s = 0;
    for (int i = lo; i < hi; ++i) s += deg[i];
    sums[t] = s;
    __syncthreads();
    for (int off = 1; off < 1024; off <<= 1) {
        int add = (t >= off) ? sums[t - off] : 0;
        __syncthreads();
        sums[t] += add;
        __syncthreads();
    }
    int run = (t > 0) ? sums[t - 1] : 0;
    for (int i = lo; i < hi; ++i) { rowptr[i] = run; run += deg[i]; }
    if (t == 1023) rowptr[N] = sums[1023];
}

__global__ void scatter_edges(const int* __restrict__ src, const int* __restrict__ dst,
                              const int* __restrict__ rowptr, int* __restrict__ cursor,
                              int* __restrict__ col, int E)
{
    int e = blockIdx.x * 256 + threadIdx.x;
    if (e >= E) return;
    int d = dst[e];
    int p = atomicAdd(&cursor[d], 1);
    col[rowptr[d] + p] = src[e];
}

// ---------- fused per-node softmax + aggregation + epilogue ----------
// one wave (64 lanes) per dst node; 4 waves / 256-thread block.
// mode 0: out[n] = elu(agg + b)              -> N x 128
// mode 1: out[n] = mean_h(agg + b)           -> N x 32
template <int MODE>
__global__ __launch_bounds__(256) void gat_node(
    const int* __restrict__ rowptr, const int* __restrict__ col,
    const float* __restrict__ el, const float* __restrict__ er,
    const float* __restrict__ Wh, const float* __restrict__ bias,
    float* __restrict__ out, int N)
{
    const int wave = threadIdx.x >> 6;
    const int lane = threadIdx.x & 63;
    const int n = blockIdx.x * 4 + wave;
    if (n >= N) return;

    const int start = rowptr[n];
    const int end   = rowptr[n + 1];
    const int h = lane >> 4;        // head this lane serves (phase 1 & 2)
    const int k = lane & 15;        // sub-lane within head group

    const float erv = er[(size_t)n * 4 + h];

    // ----- phase 1a: per-head max -----
    float m = -INFINITY;
    for (int j = start + k; j < end; j += 16) {
        float e = lrelu(el[(size_t)col[j] * 4 + h] + erv);
        m = fmaxf(m, e);
    }
#pragma unroll
    for (int off = 1; off < 16; off <<= 1)
        m = fmaxf(m, __shfl_xor(m, off, 16));

    // ----- phase 1b: per-head sum of exp -----
    float denom = 0.f;
    for (int j = start + k; j < end; j += 16) {
        float e = lrelu(el[(size_t)col[j] * 4 + h] + erv);
        denom += expf(e - m);
    }
#pragma unroll
    for (int off = 1; off < 16; off <<= 1)
        denom += __shfl_xor(denom, off, 16);
    const float inv = 1.f / (denom + EPS);

    // ----- phase 2: aggregate. lane covers cols 2*lane, 2*lane+1 (head = lane>>4) -----
    float2 acc = make_float2(0.f, 0.f);
    for (int j = start; j < end; ++j) {
        int s = col[j];
        float e = lrelu(el[(size_t)s * 4 + h] + erv);
        float alpha = expf(e - m) * inv;
        float2 w = *(const float2*)(Wh + (size_t)s * 128 + 2 * lane);
        acc.x += alpha * w.x;
        acc.y += alpha * w.y;
    }

    // ----- epilogue -----
    float bx = bias[2 * lane], by = bias[2 * lane + 1];
    if (MODE == 0) {
        float x = acc.x + bx, y = acc.y + by;
        float2 o;
        o.x = x > 0.f ? x : expm1f(x);
        o.y = y > 0.f ? y : expm1f(y);
        *(float2*)(out + (size_t)n * 128 + 2 * lane) = o;
    } else {
        // mean over heads: cols 32 apart == lanes 16 apart
        float x = acc.x + bx, y = acc.y + by;
#pragma unroll
        for (int off = 16; off < 64; off <<= 1) {
            x += __shfl_xor(x, off, 64);
            y += __shfl_xor(y, off, 64);
        }
        if (lane < 16) {
            float2 o = make_float2(0.25f * x, 0.25f * y);
            *(float2*)(out + (size_t)n * 32 + 2 * lane) = o;
        }
    }
}

// ---------- final projection: out = z2 @ Wp + bp  (N x 32 @ 32 x 512) ----------
#define NPBP 64
__global__ __launch_bounds__(256) void proj(
    const float* __restrict__ z2, const float* __restrict__ Wp,
    const float* __restrict__ bp, float* __restrict__ out, int N)
{
    __shared__ float Ws[32][256];   // 32 KB (half of Wp)
    __shared__ float zs[NPBP][32];  // 8 KB
    const int tid = threadIdx.x;
    const int node0 = blockIdx.x * NPBP;

    for (int i = tid; i < NPBP * 32; i += 256) {
        int ln = i >> 5, c = i & 31;
        int n = node0 + ln;
        zs[ln][c] = (n < N) ? z2[(size_t)n * 32 + c] : 0.f;
    }
    for (int half = 0; half < 2; ++half) {
        __syncthreads();
        for (int i = tid; i < 32 * 256; i += 256) {
            int d = i >> 8, o = i & 255;
            Ws[d][o] = Wp[(size_t)d * 512 + half * 256 + o];
        }
        __syncthreads();
        const int o = tid;
        const float bv = bp[half * 256 + o];
        for (int ln = 0; ln < NPBP; ++ln) {
            int n = node0 + ln;
            if (n >= N) break;
            float acc = bv;
#pragma unroll
            for (int d = 0; d < 32; ++d)
                acc += zs[ln][d] * Ws[d][o];
            out[(size_t)n * 512 + half * 256 + o] = acc;
        }
    }
}

extern "C" void kernel_launch(void* const* d_in, const int* in_sizes, int n_in,
                              void* d_out, int out_size, void* d_ws, size_t ws_size,
                              hipStream_t stream)
{
    const float* h   = (const float*)d_in[0];
    const int*   src = (const int*)d_in[1];
    const int*   dst = (const int*)d_in[2];
    const float* W1  = (const float*)d_in[3];
    const float* al1 = (const float*)d_in[4];
    const float* ar1 = (const float*)d_in[5];
    const float* b1  = (const float*)d_in[6];
    const float* W2  = (const float*)d_in[7];
    const float* al2 = (const float*)d_in[8];
    const float* ar2 = (const float*)d_in[9];
    const float* b2  = (const float*)d_in[10];
    const float* Wp  = (const float*)d_in[11];
    const float* bp  = (const float*)d_in[12];
    float* out = (float*)d_out;

    const int N = in_sizes[0] / D_IN;   // 50000
    const int E = in_sizes[1];          // 800000

    float* ws = (float*)d_ws;
    size_t off = 0;
    float* Wh   = ws + off; off += (size_t)N * 128;
    float* z    = ws + off; off += (size_t)N * 128;
    float* z2   = ws + off; off += (size_t)N * 32;
    float* el   = ws + off; off += (size_t)N * 4;
    float* er   = ws + off; off += (size_t)N * 4;
    int* rowptr = (int*)(ws + off); off += (size_t)N + 1;
    int* col    = (int*)(ws + off); off += (size_t)E;
    int* deg    = (int*)(ws + off); off += (size_t)N;
    int* cursor = (int*)(ws + off); off += (size_t)N;

    const int gemm_grid = (N + NPB - 1) / NPB;
    const int edge_grid = (E + 255) / 256;
    const int node_grid = (N + 3) / 4;

    // ----- CSR build (by dst) -----
    zero_ints<<<(2 * N + 255) / 256, 256, 0, stream>>>(deg, 2 * N);   // deg & cursor contiguous
    hist_dst<<<edge_grid, 256, 0, stream>>>(dst, deg, E);
    scan_deg<<<1, 1024, 0, stream>>>(deg, rowptr, N);
    scatter_edges<<<edge_grid, 256, 0, stream>>>(src, dst, rowptr, cursor, col, E);

    // ----- layer 1 -----
    gemm_node<<<gemm_grid, 256, 0, stream>>>(h, W1, al1, ar1, Wh, el, er, N);
    gat_node<0><<<node_grid, 256, 0, stream>>>(rowptr, col, el, er, Wh, b1, z, N);

    // ----- layer 2 -----
    gemm_node<<<gemm_grid, 256, 0, stream>>>(z, W2, al2, ar2, Wh, el, er, N);
    gat_node<1><<<node_grid, 256, 0, stream>>>(rowptr, col, el, er, Wh, b2, z2, N);

    // ----- projection -----
    proj<<<(N + NPBP - 1) / NPBP, 256, 0, stream>>>(z2, Wp, bp, out, N);
}

// Round 4
// 710.942 us; speedup vs baseline: 2.4248x; 1.0826x over previous
//
#include <hip/hip_runtime.h>
#include <hip/hip_bf16.h>
#include <math.h>

#define HEADS 4
#define D_HEAD 32
#define HD 128          // HEADS*D_HEAD
#define D_IN 128
#define OUT_DIM 512
#define NEG_SLOPE 0.2f
#define EPS 1e-9f

__device__ __forceinline__ float lrelu(float x) { return x > 0.f ? x : NEG_SLOPE * x; }

// ---------- node GEMM: Wh = X @ W (N x 128 @ 128 x 128), fused el/er ----------
// 32 nodes x 128 cols per 256-thread block; 4x4 register tile per thread.
// cg = tid&31 -> cols cg*4..cg*4+3 ; ng = tid>>5 -> nodes ng*4..ng*4+3.
__global__ __launch_bounds__(256) void gemm_node(
    const float* __restrict__ X, const float* __restrict__ W,
    const float* __restrict__ al, const float* __restrict__ ar,
    float* __restrict__ Wh, float* __restrict__ el, float* __restrict__ er, int N)
{
    __shared__ float Ws[64][128];   // 32 KB (half of W at a time), k-major
    __shared__ float hs[32][128];   // 16 KB node rows

    const int tid = threadIdx.x;
    const int cg  = tid & 31;
    const int ng  = tid >> 5;
    const int node0 = blockIdx.x * 32;

    // stage 32 node rows (zero-padded past N)
    for (int i = tid; i < 32 * 128; i += 256) {
        int ln = i >> 7, c = i & 127;
        int n = node0 + ln;
        hs[ln][c] = (n < N) ? X[(size_t)n * 128 + c] : 0.f;
    }

    float4 acc[4];
#pragma unroll
    for (int i = 0; i < 4; ++i) acc[i] = make_float4(0.f, 0.f, 0.f, 0.f);

    for (int kb = 0; kb < 128; kb += 64) {
        __syncthreads();
        for (int i = tid; i < 64 * 128; i += 256)
            Ws[i >> 7][i & 127] = W[(size_t)(kb + (i >> 7)) * 128 + (i & 127)];
        __syncthreads();
#pragma unroll 4
        for (int k4 = 0; k4 < 16; ++k4) {
            const int k = 4 * k4;
            float4 b0 = *(const float4*)&Ws[k + 0][cg * 4];
            float4 b1 = *(const float4*)&Ws[k + 1][cg * 4];
            float4 b2 = *(const float4*)&Ws[k + 2][cg * 4];
            float4 b3 = *(const float4*)&Ws[k + 3][cg * 4];
#pragma unroll
            for (int i = 0; i < 4; ++i) {
                float4 a = *(const float4*)&hs[ng * 4 + i][kb + k];
                acc[i].x += a.x * b0.x + a.y * b1.x + a.z * b2.x + a.w * b3.x;
                acc[i].y += a.x * b0.y + a.y * b1.y + a.z * b2.y + a.w * b3.y;
                acc[i].z += a.x * b0.z + a.y * b1.z + a.z * b2.z + a.w * b3.z;
                acc[i].w += a.x * b0.w + a.y * b1.w + a.z * b2.w + a.w * b3.w;
            }
        }
    }

    // epilogue: write Wh + fused el/er (head = cg>>3; 8 lanes per head)
    const int j0 = cg * 4;
    const int head = cg >> 3;
    const float4 alv = *(const float4*)(al + j0);
    const float4 arv = *(const float4*)(ar + j0);
#pragma unroll
    for (int i = 0; i < 4; ++i) {
        const int n = node0 + ng * 4 + i;
        if (n < N) {
            *(float4*)(Wh + (size_t)n * 128 + j0) = acc[i];
            float pl = acc[i].x * alv.x + acc[i].y * alv.y + acc[i].z * alv.z + acc[i].w * alv.w;
            float pr = acc[i].x * arv.x + acc[i].y * arv.y + acc[i].z * arv.z + acc[i].w * arv.w;
#pragma unroll
            for (int off = 1; off < 8; off <<= 1) {
                pl += __shfl_xor(pl, off, 8);
                pr += __shfl_xor(pr, off, 8);
            }
            if ((cg & 7) == 0) {
                el[(size_t)n * 4 + head] = pl;
                er[(size_t)n * 4 + head] = pr;
            }
        }
    }
}

// ---------- CSR build ----------
__global__ void zero_ints(int* __restrict__ p, int n)
{
    int t = blockIdx.x * 256 + threadIdx.x;
    if (t < n) p[t] = 0;
}

__global__ void hist_dst(const int* __restrict__ dst, int* __restrict__ deg, int E)
{
    int e = blockIdx.x * 256 + threadIdx.x;
    if (e < E) atomicAdd(&deg[dst[e]], 1);
}

// single-block exclusive scan of deg[0..N) -> rowptr[0..N]
__global__ __launch_bounds__(1024) void scan_deg(const int* __restrict__ deg,
                                                 int* __restrict__ rowptr, int N)
{
    __shared__ int sums[1024];
    const int t = threadIdx.x;
    const int chunk = (N + 1023) / 1024;
    const int lo = t * chunk;
    const int hi = min(lo + chunk, N);
    int s = 0;
    for (int i = lo; i < hi; ++i) s += deg[i];
    sums[t] = s;
    __syncthreads();
    for (int off = 1; off < 1024; off <<= 1) {
        int add = (t >= off) ? sums[t - off] : 0;
        __syncthreads();
        sums[t] += add;
        __syncthreads();
    }
    int run = (t > 0) ? sums[t - 1] : 0;
    for (int i = lo; i < hi; ++i) { rowptr[i] = run; run += deg[i]; }
    if (t == 1023) rowptr[N] = sums[1023];
}

__global__ void scatter_edges(const int* __restrict__ src, const int* __restrict__ dst,
                              const int* __restrict__ rowptr, int* __restrict__ cursor,
                              int* __restrict__ col, int E)
{
    int e = blockIdx.x * 256 + threadIdx.x;
    if (e >= E) return;
    int d = dst[e];
    int p = atomicAdd(&cursor[d], 1);
    col[rowptr[d] + p] = src[e];
}

// ---------- fused per-node softmax + aggregation + epilogue ----------
// one wave (64 lanes) per dst node; 4 waves / 256-thread block.
// mode 0: out[n] = elu(agg + b)   -> N x 128
// mode 1: out[n] = mean_h(agg+b)  -> N x 32
template <int MODE>
__global__ __launch_bounds__(256) void gat_node(
    const int* __restrict__ rowptr, const int* __restrict__ col,
    const float* __restrict__ el, const float* __restrict__ er,
    const float* __restrict__ Wh, const float* __restrict__ bias,
    float* __restrict__ out, int N)
{
    const int wave = threadIdx.x >> 6;
    const int lane = threadIdx.x & 63;
    const int n = blockIdx.x * 4 + wave;
    if (n >= N) return;

    const int start = rowptr[n];
    const int end   = rowptr[n + 1];
    const int h = lane >> 4;        // head this lane serves
    const int k = lane & 15;

    const float erv = er[(size_t)n * 4 + h];

    // per-head max
    float m = -INFINITY;
    for (int j = start + k; j < end; j += 16) {
        float e = lrelu(el[(size_t)col[j] * 4 + h] + erv);
        m = fmaxf(m, e);
    }
#pragma unroll
    for (int off = 1; off < 16; off <<= 1)
        m = fmaxf(m, __shfl_xor(m, off, 16));

    // per-head sum of exp
    float denom = 0.f;
    for (int j = start + k; j < end; j += 16) {
        float e = lrelu(el[(size_t)col[j] * 4 + h] + erv);
        denom += expf(e - m);
    }
#pragma unroll
    for (int off = 1; off < 16; off <<= 1)
        denom += __shfl_xor(denom, off, 16);
    const float inv = 1.f / (denom + EPS);

    // aggregate: lane covers cols 2*lane, 2*lane+1
    float2 acc = make_float2(0.f, 0.f);
    for (int j = start; j < end; ++j) {
        int s = col[j];
        float e = lrelu(el[(size_t)s * 4 + h] + erv);
        float alpha = expf(e - m) * inv;
        float2 w = *(const float2*)(Wh + (size_t)s * 128 + 2 * lane);
        acc.x += alpha * w.x;
        acc.y += alpha * w.y;
    }

    float bx = bias[2 * lane], by = bias[2 * lane + 1];
    if (MODE == 0) {
        float x = acc.x + bx, y = acc.y + by;
        float2 o;
        o.x = x > 0.f ? x : expm1f(x);
        o.y = y > 0.f ? y : expm1f(y);
        *(float2*)(out + (size_t)n * 128 + 2 * lane) = o;
    } else {
        float x = acc.x + bx, y = acc.y + by;
#pragma unroll
        for (int off = 16; off < 64; off <<= 1) {
            x += __shfl_xor(x, off, 64);
            y += __shfl_xor(y, off, 64);
        }
        if (lane < 16) {
            float2 o = make_float2(0.25f * x, 0.25f * y);
            *(float2*)(out + (size_t)n * 32 + 2 * lane) = o;
        }
    }
}

// ---------- final projection: out = z2 @ Wp + bp (N x 32 @ 32 x 512) ----------
// grid.y = 4 col-blocks of 128; 32 nodes per block; 4x4 register tile.
__global__ __launch_bounds__(256) void proj(
    const float* __restrict__ z2, const float* __restrict__ Wp,
    const float* __restrict__ bp, float* __restrict__ out, int N)
{
    __shared__ float Wps[32][128];  // 16 KB
    __shared__ float zs[32][32];    // 4 KB
    const int tid = threadIdx.x;
    const int cg  = tid & 31;
    const int ng  = tid >> 5;
    const int node0 = blockIdx.x * 32;
    const int cb = blockIdx.y;      // 0..3

    for (int i = tid; i < 32 * 32; i += 256) {
        int ln = i >> 5, c = i & 31;
        int n = node0 + ln;
        zs[ln][c] = (n < N) ? z2[(size_t)n * 32 + c] : 0.f;
    }
    for (int i = tid; i < 32 * 128; i += 256) {
        int k = i >> 7, c = i & 127;
        Wps[k][c] = Wp[(size_t)k * 512 + cb * 128 + c];
    }
    __syncthreads();

    float4 acc[4];
#pragma unroll
    for (int i = 0; i < 4; ++i) acc[i] = make_float4(0.f, 0.f, 0.f, 0.f);

#pragma unroll
    for (int k4 = 0; k4 < 8; ++k4) {
        const int k = 4 * k4;
        float4 b0 = *(const float4*)&Wps[k + 0][cg * 4];
        float4 b1 = *(const float4*)&Wps[k + 1][cg * 4];
        float4 b2 = *(const float4*)&Wps[k + 2][cg * 4];
        float4 b3 = *(const float4*)&Wps[k + 3][cg * 4];
#pragma unroll
        for (int i = 0; i < 4; ++i) {
            float4 a = *(const float4*)&zs[ng * 4 + i][k];
            acc[i].x += a.x * b0.x + a.y * b1.x + a.z * b2.x + a.w * b3.x;
            acc[i].y += a.x * b0.y + a.y * b1.y + a.z * b2.y + a.w * b3.y;
            acc[i].z += a.x * b0.z + a.y * b1.z + a.z * b2.z + a.w * b3.z;
            acc[i].w += a.x * b0.w + a.y * b1.w + a.z * b2.w + a.w * b3.w;
        }
    }

    const int o0 = cb * 128 + cg * 4;
    const float4 bv = *(const float4*)(bp + o0);
#pragma unroll
    for (int i = 0; i < 4; ++i) {
        const int n = node0 + ng * 4 + i;
        if (n < N) {
            float4 o;
            o.x = acc[i].x + bv.x;
            o.y = acc[i].y + bv.y;
            o.z = acc[i].z + bv.z;
            o.w = acc[i].w + bv.w;
            *(float4*)(out + (size_t)n * 512 + o0) = o;
        }
    }
}

extern "C" void kernel_launch(void* const* d_in, const int* in_sizes, int n_in,
                              void* d_out, int out_size, void* d_ws, size_t ws_size,
                              hipStream_t stream)
{
    const float* h   = (const float*)d_in[0];
    const int*   src = (const int*)d_in[1];
    const int*   dst = (const int*)d_in[2];
    const float* W1  = (const float*)d_in[3];
    const float* al1 = (const float*)d_in[4];
    const float* ar1 = (const float*)d_in[5];
    const float* b1  = (const float*)d_in[6];
    const float* W2  = (const float*)d_in[7];
    const float* al2 = (const float*)d_in[8];
    const float* ar2 = (const float*)d_in[9];
    const float* b2  = (const float*)d_in[10];
    const float* Wp  = (const float*)d_in[11];
    const float* bp  = (const float*)d_in[12];
    float* out = (float*)d_out;

    const int N = in_sizes[0] / D_IN;   // 50000
    const int E = in_sizes[1];          // 800000

    float* ws = (float*)d_ws;
    size_t off = 0;
    float* Wh   = ws + off; off += (size_t)N * 128;
    float* z    = ws + off; off += (size_t)N * 128;
    float* z2   = ws + off; off += (size_t)N * 32;
    float* el   = ws + off; off += (size_t)N * 4;
    float* er   = ws + off; off += (size_t)N * 4;
    int* rowptr = (int*)(ws + off); off += (size_t)N + 1;
    int* col    = (int*)(ws + off); off += (size_t)E;
    int* deg    = (int*)(ws + off); off += (size_t)N;
    int* cursor = (int*)(ws + off); off += (size_t)N;

    const int gemm_grid = (N + 31) / 32;
    const int edge_grid = (E + 255) / 256;
    const int node_grid = (N + 3) / 4;

    // ----- CSR build (by dst) -----
    zero_ints<<<(2 * N + 255) / 256, 256, 0, stream>>>(deg, 2 * N);   // deg & cursor contiguous
    hist_dst<<<edge_grid, 256, 0, stream>>>(dst, deg, E);
    scan_deg<<<1, 1024, 0, stream>>>(deg, rowptr, N);
    scatter_edges<<<edge_grid, 256, 0, stream>>>(src, dst, rowptr, cursor, col, E);

    // ----- layer 1 -----
    gemm_node<<<gemm_grid, 256, 0, stream>>>(h, W1, al1, ar1, Wh, el, er, N);
    gat_node<0><<<node_grid, 256, 0, stream>>>(rowptr, col, el, er, Wh, b1, z, N);

    // ----- layer 2 -----
    gemm_node<<<gemm_grid, 256, 0, stream>>>(z, W2, al2, ar2, Wh, el, er, N);
    gat_node<1><<<node_grid, 256, 0, stream>>>(rowptr, col, el, er, Wh, b2, z2, N);

    // ----- projection -----
    dim3 pgrid((N + 31) / 32, 4);
    proj<<<pgrid, 256, 0, stream>>>(z2, Wp, bp, out, N);
}

// Round 5
// 607.693 us; speedup vs baseline: 2.8368x; 1.1699x over previous
//
#include <hip/hip_runtime.h>
#include <hip/hip_bf16.h>
#include <math.h>

#define HEADS 4
#define D_HEAD 32
#define HD 128          // HEADS*D_HEAD
#define D_IN 128
#define OUT_DIM 512
#define NEG_SLOPE 0.2f
#define EPS 1e-9f

__device__ __forceinline__ float lrelu(float x) { return x > 0.f ? x : NEG_SLOPE * x; }

// ---------- node GEMM: Wh = X @ W (N x 128 @ 128 x 128), fused el/er ----------
// 32 nodes x 128 cols per 256-thread block; 4x4 register tile per thread.
__global__ __launch_bounds__(256) void gemm_node(
    const float* __restrict__ X, const float* __restrict__ W,
    const float* __restrict__ al, const float* __restrict__ ar,
    float* __restrict__ Wh, float* __restrict__ el, float* __restrict__ er, int N)
{
    __shared__ float Ws[64][128];   // 32 KB (half of W at a time), k-major
    __shared__ float hs[32][128];   // 16 KB node rows

    const int tid = threadIdx.x;
    const int cg  = tid & 31;
    const int ng  = tid >> 5;
    const int node0 = blockIdx.x * 32;

    for (int i = tid; i < 32 * 128; i += 256) {
        int ln = i >> 7, c = i & 127;
        int n = node0 + ln;
        hs[ln][c] = (n < N) ? X[(size_t)n * 128 + c] : 0.f;
    }

    float4 acc[4];
#pragma unroll
    for (int i = 0; i < 4; ++i) acc[i] = make_float4(0.f, 0.f, 0.f, 0.f);

    for (int kb = 0; kb < 128; kb += 64) {
        __syncthreads();
        for (int i = tid; i < 64 * 128; i += 256)
            Ws[i >> 7][i & 127] = W[(size_t)(kb + (i >> 7)) * 128 + (i & 127)];
        __syncthreads();
#pragma unroll 4
        for (int k4 = 0; k4 < 16; ++k4) {
            const int k = 4 * k4;
            float4 b0 = *(const float4*)&Ws[k + 0][cg * 4];
            float4 b1 = *(const float4*)&Ws[k + 1][cg * 4];
            float4 b2 = *(const float4*)&Ws[k + 2][cg * 4];
            float4 b3 = *(const float4*)&Ws[k + 3][cg * 4];
#pragma unroll
            for (int i = 0; i < 4; ++i) {
                float4 a = *(const float4*)&hs[ng * 4 + i][kb + k];
                acc[i].x += a.x * b0.x + a.y * b1.x + a.z * b2.x + a.w * b3.x;
                acc[i].y += a.x * b0.y + a.y * b1.y + a.z * b2.y + a.w * b3.y;
                acc[i].z += a.x * b0.z + a.y * b1.z + a.z * b2.z + a.w * b3.z;
                acc[i].w += a.x * b0.w + a.y * b1.w + a.z * b2.w + a.w * b3.w;
            }
        }
    }

    const int j0 = cg * 4;
    const int head = cg >> 3;
    const float4 alv = *(const float4*)(al + j0);
    const float4 arv = *(const float4*)(ar + j0);
#pragma unroll
    for (int i = 0; i < 4; ++i) {
        const int n = node0 + ng * 4 + i;
        if (n < N) {
            *(float4*)(Wh + (size_t)n * 128 + j0) = acc[i];
            float pl = acc[i].x * alv.x + acc[i].y * alv.y + acc[i].z * alv.z + acc[i].w * alv.w;
            float pr = acc[i].x * arv.x + acc[i].y * arv.y + acc[i].z * arv.z + acc[i].w * arv.w;
#pragma unroll
            for (int off = 1; off < 8; off <<= 1) {
                pl += __shfl_xor(pl, off, 8);
                pr += __shfl_xor(pr, off, 8);
            }
            if ((cg & 7) == 0) {
                el[(size_t)n * 4 + head] = pl;
                er[(size_t)n * 4 + head] = pr;
            }
        }
    }
}

// ---------- CSR build ----------
__global__ void zero_ints(int* __restrict__ p, int n)
{
    int t = blockIdx.x * 256 + threadIdx.x;
    if (t < n) p[t] = 0;
}

__global__ void hist_dst(const int* __restrict__ dst, int* __restrict__ deg, int E)
{
    int e = blockIdx.x * 256 + threadIdx.x;
    if (e < E) atomicAdd(&deg[dst[e]], 1);
}

__global__ __launch_bounds__(1024) void scan_deg(const int* __restrict__ deg,
                                                 int* __restrict__ rowptr, int N)
{
    __shared__ int sums[1024];
    const int t = threadIdx.x;
    const int chunk = (N + 1023) / 1024;
    const int lo = t * chunk;
    const int hi = min(lo + chunk, N);
    int s = 0;
    for (int i = lo; i < hi; ++i) s += deg[i];
    sums[t] = s;
    __syncthreads();
    for (int off = 1; off < 1024; off <<= 1) {
        int add = (t >= off) ? sums[t - off] : 0;
        __syncthreads();
        sums[t] += add;
        __syncthreads();
    }
    int run = (t > 0) ? sums[t - 1] : 0;
    for (int i = lo; i < hi; ++i) { rowptr[i] = run; run += deg[i]; }
    if (t == 1023) rowptr[N] = sums[1023];
}

__global__ void scatter_edges(const int* __restrict__ src, const int* __restrict__ dst,
                              const int* __restrict__ rowptr, int* __restrict__ cursor,
                              int* __restrict__ col, int E)
{
    int e = blockIdx.x * 256 + threadIdx.x;
    if (e >= E) return;
    int d = dst[e];
    int p = atomicAdd(&cursor[d], 1);
    col[rowptr[d] + p] = src[e];
}

// ---------- fused per-node softmax + aggregation + epilogue ----------
// one wave per dst node; phase 2 processes 2 edges/iter (half-wave each, float4).
// mode 0: out[n] = elu(agg + b)   -> N x 128
// mode 1: out[n] = mean_h(agg+b)  -> N x 32
template <int MODE>
__global__ __launch_bounds__(256) void gat_node(
    const int* __restrict__ rowptr, const int* __restrict__ col,
    const float* __restrict__ el, const float* __restrict__ er,
    const float* __restrict__ Wh, const float* __restrict__ bias,
    float* __restrict__ out, int N)
{
    const int wave = threadIdx.x >> 6;
    const int lane = threadIdx.x & 63;
    const int n = blockIdx.x * 4 + wave;
    if (n >= N) return;

    const int start = rowptr[n];
    const int end   = rowptr[n + 1];

    // ----- phase 1: per-head max + sum of exp (16 lanes per head) -----
    const int h1 = lane >> 4;
    const int k1 = lane & 15;
    const float erv1 = er[(size_t)n * 4 + h1];

    float m = -INFINITY;
    for (int j = start + k1; j < end; j += 16)
        m = fmaxf(m, lrelu(el[(size_t)col[j] * 4 + h1] + erv1));
#pragma unroll
    for (int off = 1; off < 16; off <<= 1)
        m = fmaxf(m, __shfl_xor(m, off, 16));

    float denom = 0.f;
    for (int j = start + k1; j < end; j += 16)
        denom += expf(lrelu(el[(size_t)col[j] * 4 + h1] + erv1) - m);
#pragma unroll
    for (int off = 1; off < 16; off <<= 1)
        denom += __shfl_xor(denom, off, 16);
    const float inv = 1.f / (denom + EPS);

    // ----- phase 2: half-wave per edge, float4 per lane -----
    const int sub = lane >> 5;          // which edge of the pair
    const int q   = lane & 31;          // col group: cols 4q..4q+3
    const int h2  = q >> 3;             // head for these cols
    const float erv2 = er[(size_t)n * 4 + h2];
    const float m2   = __shfl(m,   h2 * 16, 64);
    const float inv2 = __shfl(inv, h2 * 16, 64);

    float4 acc = make_float4(0.f, 0.f, 0.f, 0.f);
    for (int j = start + sub; j < end; j += 2) {
        int s = col[j];
        float e = lrelu(el[(size_t)s * 4 + h2] + erv2);
        float alpha = expf(e - m2) * inv2;
        float4 w = *(const float4*)(Wh + (size_t)s * 128 + 4 * q);
        acc.x += alpha * w.x;
        acc.y += alpha * w.y;
        acc.z += alpha * w.z;
        acc.w += alpha * w.w;
    }
    acc.x += __shfl_xor(acc.x, 32, 64);
    acc.y += __shfl_xor(acc.y, 32, 64);
    acc.z += __shfl_xor(acc.z, 32, 64);
    acc.w += __shfl_xor(acc.w, 32, 64);

    const float4 bv = *(const float4*)(bias + 4 * q);
    if (MODE == 0) {
        if (sub == 0) {
            float4 o;
            float x;
            x = acc.x + bv.x; o.x = x > 0.f ? x : expm1f(x);
            x = acc.y + bv.y; o.y = x > 0.f ? x : expm1f(x);
            x = acc.z + bv.z; o.z = x > 0.f ? x : expm1f(x);
            x = acc.w + bv.w; o.w = x > 0.f ? x : expm1f(x);
            *(float4*)(out + (size_t)n * 128 + 4 * q) = o;
        }
    } else {
        // mean over heads: head h lives in lanes q ^ {8,16,24}
        float x = acc.x + bv.x, y = acc.y + bv.y, z = acc.z + bv.z, w = acc.w + bv.w;
        x += __shfl_xor(x, 8, 64);  x += __shfl_xor(x, 16, 64);
        y += __shfl_xor(y, 8, 64);  y += __shfl_xor(y, 16, 64);
        z += __shfl_xor(z, 8, 64);  z += __shfl_xor(z, 16, 64);
        w += __shfl_xor(w, 8, 64);  w += __shfl_xor(w, 16, 64);
        if (lane < 8) {
            float4 o = make_float4(0.25f * x, 0.25f * y, 0.25f * z, 0.25f * w);
            *(float4*)(out + (size_t)n * 32 + 4 * q) = o;
        }
    }
}

// ---------- final projection: out = z2 @ Wp + bp (N x 32 @ 32 x 512) ----------
// Persistent batches: grid (196, 4) ~= all-resident (3 blocks/CU at VGPR~148).
// Each block stages its 32x128 Wp tile ONCE, then loops node-batches of 32:
// stage 4 KB z2 -> 4x4-tile compute -> stream 16 KB stores.
#define PROJ_GX 196
__global__ __launch_bounds__(256) void proj(
    const float* __restrict__ z2, const float* __restrict__ Wp,
    const float* __restrict__ bp, float* __restrict__ out, int N)
{
    __shared__ float Wps[32][128];  // 16 KB
    __shared__ float zs[32][32];    // 4 KB
    const int tid = threadIdx.x;
    const int cg  = tid & 31;
    const int ng  = tid >> 5;
    const int cb  = blockIdx.y;     // 0..3

    // stage Wp tile once
    for (int i = tid; i < 32 * 32; i += 256) {
        int k = i >> 5, c4 = (i & 31) * 4;
        *(float4*)&Wps[k][c4] = *(const float4*)(Wp + (size_t)k * 512 + cb * 128 + c4);
    }

    const int o0 = cb * 128 + cg * 4;
    const float4 bv = *(const float4*)(bp + o0);
    const int NB = (N + 31) >> 5;

    const int zln = tid >> 3;            // node row this thread stages
    const int zc4 = (tid & 7) * 4;       // 4-float chunk

    for (int nb = blockIdx.x; nb < NB; nb += PROJ_GX) {
        const int node0 = nb << 5;
        // stage 32 z2 rows (256 threads x 1 float4 = 4 KB)
        {
            int nn = node0 + zln;
            float4 v = (nn < N) ? *(const float4*)(z2 + (size_t)nn * 32 + zc4)
                                : make_float4(0.f, 0.f, 0.f, 0.f);
            *(float4*)&zs[zln][zc4] = v;
        }
        __syncthreads();

        float4 acc[4];
#pragma unroll
        for (int i = 0; i < 4; ++i) acc[i] = make_float4(0.f, 0.f, 0.f, 0.f);

#pragma unroll
        for (int k4 = 0; k4 < 8; ++k4) {
            const int k = 4 * k4;
            float4 b0 = *(const float4*)&Wps[k + 0][cg * 4];
            float4 b1 = *(const float4*)&Wps[k + 1][cg * 4];
            float4 b2 = *(const float4*)&Wps[k + 2][cg * 4];
            float4 b3 = *(const float4*)&Wps[k + 3][cg * 4];
#pragma unroll
            for (int i = 0; i < 4; ++i) {
                float4 a = *(const float4*)&zs[ng * 4 + i][k];
                acc[i].x += a.x * b0.x + a.y * b1.x + a.z * b2.x + a.w * b3.x;
                acc[i].y += a.x * b0.y + a.y * b1.y + a.z * b2.y + a.w * b3.y;
                acc[i].z += a.x * b0.z + a.y * b1.z + a.z * b2.z + a.w * b3.z;
                acc[i].w += a.x * b0.w + a.y * b1.w + a.z * b2.w + a.w * b3.w;
            }
        }
        __syncthreads();   // zs reads done before next batch overwrites

#pragma unroll
        for (int i = 0; i < 4; ++i) {
            const int n = node0 + ng * 4 + i;
            if (n < N) {
                float4 o;
                o.x = acc[i].x + bv.x;
                o.y = acc[i].y + bv.y;
                o.z = acc[i].z + bv.z;
                o.w = acc[i].w + bv.w;
                *(float4*)(out + (size_t)n * 512 + o0) = o;
            }
        }
    }
}

extern "C" void kernel_launch(void* const* d_in, const int* in_sizes, int n_in,
                              void* d_out, int out_size, void* d_ws, size_t ws_size,
                              hipStream_t stream)
{
    const float* h   = (const float*)d_in[0];
    const int*   src = (const int*)d_in[1];
    const int*   dst = (const int*)d_in[2];
    const float* W1  = (const float*)d_in[3];
    const float* al1 = (const float*)d_in[4];
    const float* ar1 = (const float*)d_in[5];
    const float* b1  = (const float*)d_in[6];
    const float* W2  = (const float*)d_in[7];
    const float* al2 = (const float*)d_in[8];
    const float* ar2 = (const float*)d_in[9];
    const float* b2  = (const float*)d_in[10];
    const float* Wp  = (const float*)d_in[11];
    const float* bp  = (const float*)d_in[12];
    float* out = (float*)d_out;

    const int N = in_sizes[0] / D_IN;   // 50000
    const int E = in_sizes[1];          // 800000

    float* ws = (float*)d_ws;
    size_t off = 0;
    float* Wh   = ws + off; off += (size_t)N * 128;
    float* z    = ws + off; off += (size_t)N * 128;
    float* z2   = ws + off; off += (size_t)N * 32;
    float* el   = ws + off; off += (size_t)N * 4;
    float* er   = ws + off; off += (size_t)N * 4;
    int* rowptr = (int*)(ws + off); off += (size_t)N + 1;
    int* col    = (int*)(ws + off); off += (size_t)E;
    int* deg    = (int*)(ws + off); off += (size_t)N;
    int* cursor = (int*)(ws + off); off += (size_t)N;

    const int gemm_grid = (N + 31) / 32;
    const int edge_grid = (E + 255) / 256;
    const int node_grid = (N + 3) / 4;

    // ----- CSR build (by dst) -----
    zero_ints<<<(2 * N + 255) / 256, 256, 0, stream>>>(deg, 2 * N);   // deg & cursor contiguous
    hist_dst<<<edge_grid, 256, 0, stream>>>(dst, deg, E);
    scan_deg<<<1, 1024, 0, stream>>>(deg, rowptr, N);
    scatter_edges<<<edge_grid, 256, 0, stream>>>(src, dst, rowptr, cursor, col, E);

    // ----- layer 1 -----
    gemm_node<<<gemm_grid, 256, 0, stream>>>(h, W1, al1, ar1, Wh, el, er, N);
    gat_node<0><<<node_grid, 256, 0, stream>>>(rowptr, col, el, er, Wh, b1, z, N);

    // ----- layer 2 -----
    gemm_node<<<gemm_grid, 256, 0, stream>>>(z, W2, al2, ar2, Wh, el, er, N);
    gat_node<1><<<node_grid, 256, 0, stream>>>(rowptr, col, el, er, Wh, b2, z2, N);

    // ----- projection -----
    dim3 pgrid(PROJ_GX, 4);
    proj<<<pgrid, 256, 0, stream>>>(z2, Wp, bp, out, N);
}